// Round 5
// baseline (1135.621 us; speedup 1.0000x reference)
//
#include <hip/hip_runtime.h>

#define N_NODES 100000
#define N_EDGES 1600000
#define D_IN 128
#define D 64

#define NBLK 1000          // scatter blocks
#define EPB  1600          // edges per scatter block (NBLK*EPB == N_EDGES)
#define NB2  391           // coarse buckets: dst>>8, max 99999>>8 = 390
#define SCAN_T 1024

__device__ __forceinline__ float bf2f(unsigned short u) {
    union { unsigned int i; float f; } q; q.i = ((unsigned int)u) << 16; return q.f;
}
__device__ __forceinline__ unsigned short f2bf(float f) {
    unsigned int u = __float_as_uint(f);
    unsigned int r = (u + 0x7FFFu + ((u >> 16) & 1u)) >> 16;   // RNE
    return (unsigned short)r;
}
__device__ __forceinline__ void acc4(float4& a, ushort4 v) {
    a.x += bf2f(v.x); a.y += bf2f(v.y); a.z += bf2f(v.z); a.w += bf2f(v.w);
}

// ============ CSR build: two-level counting sort, LDS atomics only ============

// A1: per-block histogram over coarse buckets
__global__ __launch_bounds__(256) void k_hist1(const int* __restrict__ dst,
                                               int* __restrict__ bh) {
    __shared__ int h[NB2];
    int t = threadIdx.x;
    for (int i = t; i < NB2; i += 256) h[i] = 0;
    __syncthreads();
    int base = blockIdx.x * EPB;
    for (int i = t; i < EPB; i += 256) atomicAdd(&h[dst[base + i] >> 8], 1);
    __syncthreads();
    for (int i = t; i < NB2; i += 256) bh[i * NBLK + blockIdx.x] = h[i];
}

// A2: global exclusive scan over bh[NB2*NBLK], in place
__global__ __launch_bounds__(SCAN_T) void k_scan(int* __restrict__ bh) {
    __shared__ int s[SCAN_T];
    int t = threadIdx.x;
    const int M = NB2 * NBLK;
    const int C = (M + SCAN_T - 1) / SCAN_T;
    int lo = t * C, hi = lo + C; if (hi > M) hi = M;
    int sum = 0;
    for (int i = lo; i < hi; i++) sum += bh[i];
    s[t] = sum;
    __syncthreads();
    for (int o = 1; o < SCAN_T; o <<= 1) {
        int v = (t >= o) ? s[t - o] : 0;
        __syncthreads();
        s[t] += v;
        __syncthreads();
    }
    int run = (t > 0) ? s[t - 1] : 0;
    for (int i = lo; i < hi; i++) { int v = bh[i]; bh[i] = run; run += v; }
}

// A3: scatter (dst,src) pairs into bucket-sorted tmp
__global__ __launch_bounds__(256) void k_scatter1(const int* __restrict__ src,
                                                  const int* __restrict__ dst,
                                                  const int* __restrict__ bh,
                                                  uint2* __restrict__ tmp) {
    __shared__ int cur[NB2];
    int t = threadIdx.x;
    for (int i = t; i < NB2; i += 256) cur[i] = bh[i * NBLK + blockIdx.x];
    __syncthreads();
    int base = blockIdx.x * EPB;
    for (int i = t; i < EPB; i += 256) {
        int d = dst[base + i];
        int sv = src[base + i];
        int p = atomicAdd(&cur[d >> 8], 1);
        tmp[p] = make_uint2((unsigned)d, (unsigned)sv);
    }
}

// B: per-bucket fine sort -> offs + csr (256 nodes/bucket, all in LDS)
__global__ __launch_bounds__(256) void k_build(const uint2* __restrict__ tmp,
                                               const int* __restrict__ bh,
                                               int* __restrict__ offs,
                                               int* __restrict__ csr) {
    __shared__ int deg[256];
    __shared__ int s[256];
    __shared__ int cur[256];
    int b = blockIdx.x;
    int t = threadIdx.x;
    int e0 = bh[b * NBLK];
    int e1 = (b == NB2 - 1) ? N_EDGES : bh[(b + 1) * NBLK];
    deg[t] = 0;
    __syncthreads();
    for (int i = e0 + t; i < e1; i += 256) atomicAdd(&deg[tmp[i].x & 255u], 1);
    __syncthreads();
    int v = deg[t];
    s[t] = v;
    __syncthreads();
    for (int o = 1; o < 256; o <<= 1) {
        int x = (t >= o) ? s[t - o] : 0;
        __syncthreads();
        s[t] += x;
        __syncthreads();
    }
    int start = e0 + s[t] - v;      // exclusive
    int node = b * 256 + t;
    if (node < N_NODES) offs[node] = start;
    cur[t] = start;
    __syncthreads();
    for (int i = e0 + t; i < e1; i += 256) {
        uint2 p = tmp[i];
        int pos = atomicAdd(&cur[p.x & 255u], 1);
        csr[pos] = (int)p.y;
    }
    if (b == 0 && t == 0) offs[N_NODES] = N_EDGES;
}

// ---------------- z = x @ w1a  (128 -> 64, no bias), z stored bf16 ----------------
__global__ __launch_bounds__(256) void k_gemm1(const float* __restrict__ x,
                                               const float* __restrict__ w,
                                               unsigned short* __restrict__ z) {
    __shared__ float ws[D_IN][D];        // 32 KB
    __shared__ float xs[16][D_IN + 1];
    int t = threadIdx.x;
    {
        const float4* w4 = (const float4*)w;
        float4* s4 = (float4*)&ws[0][0];
        for (int i = t; i < (D_IN * D) / 4; i += 256) s4[i] = w4[i];
    }
    int r = t >> 4, c = t & 15;
    __syncthreads();
    for (int base = blockIdx.x * 16; base < N_NODES; base += gridDim.x * 16) {
        for (int i = t; i < 16 * (D_IN / 4); i += 256) {
            int row = i >> 5, k4 = i & 31;
            float4 v = ((const float4*)(x + (size_t)(base + row) * D_IN))[k4];
            xs[row][k4 * 4 + 0] = v.x; xs[row][k4 * 4 + 1] = v.y;
            xs[row][k4 * 4 + 2] = v.z; xs[row][k4 * 4 + 3] = v.w;
        }
        __syncthreads();
        float4 acc = {0.f, 0.f, 0.f, 0.f};
        for (int k = 0; k < D_IN; k++) {
            float xv = xs[r][k];
            float4 wv = *(const float4*)&ws[k][c * 4];
            acc.x += xv * wv.x; acc.y += xv * wv.y;
            acc.z += xv * wv.z; acc.w += xv * wv.w;
        }
        ushort4 p;
        p.x = f2bf(acc.x); p.y = f2bf(acc.y); p.z = f2bf(acc.z); p.w = f2bf(acc.w);
        *(ushort4*)(z + (size_t)(base + r) * D + c * 4) = p;
        __syncthreads();
    }
}

// clamped depth-16 gather accumulate: always 16 loads in flight, masked adds
__device__ __forceinline__ void gather16(float4& acc, const unsigned short* __restrict__ zz,
                                         const int* __restrict__ csr,
                                         int e0, int e1, size_t c4) {
    for (int e = e0; e < e1; e += 16) {
        int idx[16];
        #pragma unroll
        for (int k = 0; k < 16; k++) {
            int ee = e + k;
            idx[k] = csr[ee < e1 ? ee : e1 - 1];
        }
        ushort4 vv[16];
        #pragma unroll
        for (int k = 0; k < 16; k++)
            vv[k] = *(const ushort4*)(zz + (size_t)idx[k] * D + c4);
        #pragma unroll
        for (int k = 0; k < 16; k++) {
            if (e + k < e1) acc4(acc, vv[k]);
        }
    }
}

// ---------------- conv1 fused: agg(z)+b1a+relu, @w1b+b1b relu, @w2a -> u (bf16) ----------------
__global__ __launch_bounds__(256, 6) void k_conv1(const unsigned short* __restrict__ z,
                                                  const int* __restrict__ offs,
                                                  const int* __restrict__ csr,
                                                  const float* __restrict__ b1a,
                                                  const float* __restrict__ w1b,
                                                  const float* __restrict__ b1b,
                                                  const float* __restrict__ w2a,
                                                  unsigned short* __restrict__ u) {
    __shared__ unsigned short w1s[D][D];   // 8 KB bf16
    __shared__ unsigned short w2s[D][D];   // 8 KB bf16
    __shared__ float h1s[16][D + 1];
    __shared__ float h2s[16][D + 1];
    int t = threadIdx.x;
    int r = t >> 4, c = t & 15;
    {
        for (int i = t; i < (D * D) / 4; i += 256) {
            float4 a = ((const float4*)w1b)[i];
            ushort4 p; p.x = f2bf(a.x); p.y = f2bf(a.y); p.z = f2bf(a.z); p.w = f2bf(a.w);
            *(ushort4*)&(&w1s[0][0])[i * 4] = p;
            float4 b = ((const float4*)w2a)[i];
            ushort4 q; q.x = f2bf(b.x); q.y = f2bf(b.y); q.z = f2bf(b.z); q.w = f2bf(b.w);
            *(ushort4*)&(&w2s[0][0])[i * 4] = q;
        }
    }
    float4 vb1a = ((const float4*)b1a)[c];
    float4 vb1b = ((const float4*)b1b)[c];
    __syncthreads();

    const size_t c4 = (size_t)(c * 4);
    for (int base = blockIdx.x * 16; base < N_NODES; base += gridDim.x * 16) {
        int node = base + r;   // N_NODES % 16 == 0
        float4 acc = {vb1a.x, vb1a.y, vb1a.z, vb1a.w};
        acc4(acc, *(const ushort4*)(z + (size_t)node * D + c4));
        int e0 = offs[node], e1 = offs[node + 1];
        gather16(acc, z, csr, e0, e1, c4);
        h1s[r][c * 4 + 0] = fmaxf(acc.x, 0.f);
        h1s[r][c * 4 + 1] = fmaxf(acc.y, 0.f);
        h1s[r][c * 4 + 2] = fmaxf(acc.z, 0.f);
        h1s[r][c * 4 + 3] = fmaxf(acc.w, 0.f);
        __syncthreads();
        // --- h2 = relu(h1 @ w1b + b1b) ---
        float4 a2 = vb1b;
        for (int k = 0; k < D; k++) {
            float hv = h1s[r][k];
            ushort4 wv = *(const ushort4*)&w1s[k][c * 4];
            a2.x += hv * bf2f(wv.x); a2.y += hv * bf2f(wv.y);
            a2.z += hv * bf2f(wv.z); a2.w += hv * bf2f(wv.w);
        }
        h2s[r][c * 4 + 0] = fmaxf(a2.x, 0.f);
        h2s[r][c * 4 + 1] = fmaxf(a2.y, 0.f);
        h2s[r][c * 4 + 2] = fmaxf(a2.z, 0.f);
        h2s[r][c * 4 + 3] = fmaxf(a2.w, 0.f);
        __syncthreads();
        // --- u = h2 @ w2a  (bias b2a applied in conv2 agg), u stored bf16 ---
        float4 a3 = {0.f, 0.f, 0.f, 0.f};
        for (int k = 0; k < D; k++) {
            float hv = h2s[r][k];
            ushort4 wv = *(const ushort4*)&w2s[k][c * 4];
            a3.x += hv * bf2f(wv.x); a3.y += hv * bf2f(wv.y);
            a3.z += hv * bf2f(wv.z); a3.w += hv * bf2f(wv.w);
        }
        ushort4 p;
        p.x = f2bf(a3.x); p.y = f2bf(a3.y); p.z = f2bf(a3.z); p.w = f2bf(a3.w);
        *(ushort4*)(u + (size_t)node * D + c4) = p;
        __syncthreads();
    }
}

// ---------------- conv2 fused: agg(u) + b2a + relu -> column sum ----------------
__global__ __launch_bounds__(256) void k_conv2(const unsigned short* __restrict__ u,
                                               const int* __restrict__ offs,
                                               const int* __restrict__ csr,
                                               const float* __restrict__ b2a,
                                               float* __restrict__ colsum) {
    __shared__ float red[16][D + 1];
    int t = threadIdx.x;
    int r = t >> 4, c = t & 15;
    float4 vb = ((const float4*)b2a)[c];
    float4 cs = {0.f, 0.f, 0.f, 0.f};
    const size_t c4 = (size_t)(c * 4);
    for (int base = blockIdx.x * 16; base < N_NODES; base += gridDim.x * 16) {
        int node = base + r;
        float4 acc = {vb.x, vb.y, vb.z, vb.w};
        acc4(acc, *(const ushort4*)(u + (size_t)node * D + c4));
        int e0 = offs[node], e1 = offs[node + 1];
        gather16(acc, u, csr, e0, e1, c4);
        cs.x += fmaxf(acc.x, 0.f); cs.y += fmaxf(acc.y, 0.f);
        cs.z += fmaxf(acc.z, 0.f); cs.w += fmaxf(acc.w, 0.f);
    }
    red[r][c * 4 + 0] = cs.x; red[r][c * 4 + 1] = cs.y;
    red[r][c * 4 + 2] = cs.z; red[r][c * 4 + 3] = cs.w;
    __syncthreads();
    if (r == 0) {
        float4 tot = {0.f, 0.f, 0.f, 0.f};
        for (int rr = 0; rr < 16; rr++) {
            tot.x += red[rr][c * 4 + 0]; tot.y += red[rr][c * 4 + 1];
            tot.z += red[rr][c * 4 + 2]; tot.w += red[rr][c * 4 + 3];
        }
        atomicAdd(&colsum[c * 4 + 0], tot.x);
        atomicAdd(&colsum[c * 4 + 1], tot.y);
        atomicAdd(&colsum[c * 4 + 2], tot.z);
        atomicAdd(&colsum[c * 4 + 3], tot.w);
    }
}

// ---------------- out = colsum @ w2b + N * b2b ----------------
__global__ void k_final(const float* __restrict__ colsum, const float* __restrict__ w2b,
                        const float* __restrict__ b2b, float* __restrict__ out) {
    int j = threadIdx.x;
    float acc = (float)N_NODES * b2b[j];
    for (int k = 0; k < D; k++) acc += colsum[k] * w2b[k * D + j];
    out[j] = acc;
}

// ---------------- launch ----------------

extern "C" void kernel_launch(void* const* d_in, const int* in_sizes, int n_in,
                              void* d_out, int out_size, void* d_ws, size_t ws_size,
                              hipStream_t stream) {
    const float* x   = (const float*)d_in[0];
    const int*   ei  = (const int*)d_in[1];
    const float* w1a = (const float*)d_in[2];
    const float* b1a = (const float*)d_in[3];
    const float* w1b = (const float*)d_in[4];
    const float* b1b = (const float*)d_in[5];
    const float* w2a = (const float*)d_in[6];
    const float* b2a = (const float*)d_in[7];
    const float* w2b = (const float*)d_in[8];
    const float* b2b = (const float*)d_in[9];
    float* out = (float*)d_out;

    const int* srcp = ei;
    const int* dstp = ei + N_EDGES;

    char* ws = (char*)d_ws;
    unsigned short* z = (unsigned short*)(ws + 0);        // 12,800,000 B
    unsigned short* u = (unsigned short*)(ws + 12800000); // 12,800,000 B
    uint2* tmp    = (uint2*)(ws + 25600000);              // 12,800,000 B
    int*   csr    = (int*)(ws + 38400000);                // 6,400,000 B
    int*   bh     = (int*)(ws + 44800000);                // 1,564,000 B
    int*   offs   = (int*)(ws + 46364000);                // 400,004 B
    float* colsum = (float*)(ws + 46764032);              // 256 B

    hipMemsetAsync(colsum, 0, D * sizeof(float), stream);

    k_hist1   <<<NBLK, 256, 0, stream>>>(dstp, bh);
    k_scan    <<<1, SCAN_T, 0, stream>>>(bh);
    k_scatter1<<<NBLK, 256, 0, stream>>>(srcp, dstp, bh, tmp);
    k_build   <<<NB2, 256, 0, stream>>>(tmp, bh, offs, csr);

    k_gemm1<<<2048, 256, 0, stream>>>(x, w1a, z);
    k_conv1<<<2048, 256, 0, stream>>>(z, offs, csr, b1a, w1b, b1b, w2a, u);
    k_conv2<<<2048, 256, 0, stream>>>(u, offs, csr, b2a, colsum);
    k_final<<<1, 64, 0, stream>>>(colsum, w2b, b2b, out);
}

// Round 6
// 492.933 us; speedup vs baseline: 2.3038x; 2.3038x over previous
//
#include <hip/hip_runtime.h>

#define N_NODES 100000
#define N_EDGES 1600000
#define D_IN 128
#define D 64

#define NBLK 1000          // scatter blocks
#define EPB  1600          // edges per scatter block (NBLK*EPB == N_EDGES)
#define NB2  391           // coarse buckets: dst>>8, max 99999>>8 = 390
#define SC_M  (NB2 * NBLK)                  // 391,000 scan elements
#define SC_CH 1024                          // elements per scan chunk
#define SC_NB ((SC_M + SC_CH - 1) / SC_CH)  // 382 chunks

__device__ __forceinline__ float bf2f(unsigned short u) {
    union { unsigned int i; float f; } q; q.i = ((unsigned int)u) << 16; return q.f;
}
__device__ __forceinline__ unsigned short f2bf(float f) {
    unsigned int u = __float_as_uint(f);
    unsigned int r = (u + 0x7FFFu + ((u >> 16) & 1u)) >> 16;   // RNE
    return (unsigned short)r;
}
__device__ __forceinline__ void acc4(float4& a, ushort4 v) {
    a.x += bf2f(v.x); a.y += bf2f(v.y); a.z += bf2f(v.z); a.w += bf2f(v.w);
}

// ============ CSR build: two-level counting sort, LDS atomics only ============

// A1: per-block histogram over coarse buckets
__global__ __launch_bounds__(256) void k_hist1(const int* __restrict__ dst,
                                               int* __restrict__ bh) {
    __shared__ int h[NB2];
    int t = threadIdx.x;
    for (int i = t; i < NB2; i += 256) h[i] = 0;
    __syncthreads();
    int base = blockIdx.x * EPB;
    for (int i = t; i < EPB; i += 256) atomicAdd(&h[dst[base + i] >> 8], 1);
    __syncthreads();
    for (int i = t; i < NB2; i += 256) bh[i * NBLK + blockIdx.x] = h[i];
}

// A2a: per-chunk sums (1024 elements / block of 256, int4 loads)
__global__ __launch_bounds__(256) void k_scanA(const int* __restrict__ bh,
                                               int* __restrict__ part) {
    __shared__ int s[256];
    int t = threadIdx.x;
    int base = blockIdx.x * SC_CH + t * 4;
    int sum = 0;
    if (base + 3 < SC_M) {
        int4 v = *(const int4*)(bh + base);
        sum = (v.x + v.y) + (v.z + v.w);
    } else {
        for (int k = 0; k < 4; k++) if (base + k < SC_M) sum += bh[base + k];
    }
    s[t] = sum;
    __syncthreads();
    for (int o = 128; o > 0; o >>= 1) {
        if (t < o) s[t] += s[t + o];
        __syncthreads();
    }
    if (t == 0) part[blockIdx.x] = s[0];
}

// A2b: exclusive scan of the 382 chunk sums (1 block)
__global__ __launch_bounds__(512) void k_scanB(int* __restrict__ part) {
    __shared__ int s[512];
    int t = threadIdx.x;
    int v = (t < SC_NB) ? part[t] : 0;
    s[t] = v;
    __syncthreads();
    for (int o = 1; o < 512; o <<= 1) {
        int x = (t >= o) ? s[t - o] : 0;
        __syncthreads();
        s[t] += x;
        __syncthreads();
    }
    if (t < SC_NB) part[t] = s[t] - v;   // exclusive
}

// A2c: local exclusive scan + chunk base, write back in place
__global__ __launch_bounds__(256) void k_scanC(int* __restrict__ bh,
                                               const int* __restrict__ part) {
    __shared__ int s[256];
    int t = threadIdx.x;
    int base = blockIdx.x * SC_CH + t * 4;
    int4 v = {0, 0, 0, 0};
    if (base + 3 < SC_M) v = *(const int4*)(bh + base);
    else { for (int k = 0; k < 4; k++) if (base + k < SC_M) (&v.x)[k] = bh[base + k]; }
    int sum = (v.x + v.y) + (v.z + v.w);
    s[t] = sum;
    __syncthreads();
    for (int o = 1; o < 256; o <<= 1) {
        int x = (t >= o) ? s[t - o] : 0;
        __syncthreads();
        s[t] += x;
        __syncthreads();
    }
    int run = part[blockIdx.x] + s[t] - sum;   // exclusive base for this thread
    int4 w;
    w.x = run; run += v.x;
    w.y = run; run += v.y;
    w.z = run; run += v.z;
    w.w = run;
    if (base + 3 < SC_M) *(int4*)(bh + base) = w;
    else { for (int k = 0; k < 4; k++) if (base + k < SC_M) bh[base + k] = (&w.x)[k]; }
}

// A3: scatter (dst,src) pairs into bucket-sorted tmp
__global__ __launch_bounds__(256) void k_scatter1(const int* __restrict__ src,
                                                  const int* __restrict__ dst,
                                                  const int* __restrict__ bh,
                                                  uint2* __restrict__ tmp) {
    __shared__ int cur[NB2];
    int t = threadIdx.x;
    for (int i = t; i < NB2; i += 256) cur[i] = bh[i * NBLK + blockIdx.x];
    __syncthreads();
    int base = blockIdx.x * EPB;
    for (int i = t; i < EPB; i += 256) {
        int d = dst[base + i];
        int sv = src[base + i];
        int p = atomicAdd(&cur[d >> 8], 1);
        tmp[p] = make_uint2((unsigned)d, (unsigned)sv);
    }
}

// B: per-bucket fine sort -> offs + csr (256 nodes/bucket, all in LDS)
__global__ __launch_bounds__(256) void k_build(const uint2* __restrict__ tmp,
                                               const int* __restrict__ bh,
                                               int* __restrict__ offs,
                                               int* __restrict__ csr) {
    __shared__ int deg[256];
    __shared__ int s[256];
    __shared__ int cur[256];
    int b = blockIdx.x;
    int t = threadIdx.x;
    int e0 = bh[b * NBLK];
    int e1 = (b == NB2 - 1) ? N_EDGES : bh[(b + 1) * NBLK];
    deg[t] = 0;
    __syncthreads();
    for (int i = e0 + t; i < e1; i += 256) atomicAdd(&deg[tmp[i].x & 255u], 1);
    __syncthreads();
    int v = deg[t];
    s[t] = v;
    __syncthreads();
    for (int o = 1; o < 256; o <<= 1) {
        int x = (t >= o) ? s[t - o] : 0;
        __syncthreads();
        s[t] += x;
        __syncthreads();
    }
    int start = e0 + s[t] - v;      // exclusive
    int node = b * 256 + t;
    if (node < N_NODES) offs[node] = start;
    cur[t] = start;
    __syncthreads();
    for (int i = e0 + t; i < e1; i += 256) {
        uint2 p = tmp[i];
        int pos = atomicAdd(&cur[p.x & 255u], 1);
        csr[pos] = (int)p.y;
    }
    if (b == 0 && t == 0) offs[N_NODES] = N_EDGES;
}

// ---------------- z = x @ w1a  (128 -> 64, no bias), z stored bf16 ----------------
__global__ __launch_bounds__(256) void k_gemm1(const float* __restrict__ x,
                                               const float* __restrict__ w,
                                               unsigned short* __restrict__ z) {
    __shared__ float ws[D_IN][D];        // 32 KB
    __shared__ float xs[16][D_IN + 1];
    int t = threadIdx.x;
    {
        const float4* w4 = (const float4*)w;
        float4* s4 = (float4*)&ws[0][0];
        for (int i = t; i < (D_IN * D) / 4; i += 256) s4[i] = w4[i];
    }
    int r = t >> 4, c = t & 15;
    __syncthreads();
    for (int base = blockIdx.x * 16; base < N_NODES; base += gridDim.x * 16) {
        for (int i = t; i < 16 * (D_IN / 4); i += 256) {
            int row = i >> 5, k4 = i & 31;
            float4 v = ((const float4*)(x + (size_t)(base + row) * D_IN))[k4];
            xs[row][k4 * 4 + 0] = v.x; xs[row][k4 * 4 + 1] = v.y;
            xs[row][k4 * 4 + 2] = v.z; xs[row][k4 * 4 + 3] = v.w;
        }
        __syncthreads();
        float4 acc = {0.f, 0.f, 0.f, 0.f};
        for (int k = 0; k < D_IN; k++) {
            float xv = xs[r][k];
            float4 wv = *(const float4*)&ws[k][c * 4];
            acc.x += xv * wv.x; acc.y += xv * wv.y;
            acc.z += xv * wv.z; acc.w += xv * wv.w;
        }
        ushort4 p;
        p.x = f2bf(acc.x); p.y = f2bf(acc.y); p.z = f2bf(acc.z); p.w = f2bf(acc.w);
        *(ushort4*)(z + (size_t)(base + r) * D + c * 4) = p;
        __syncthreads();
    }
}

// clamped depth-16 gather accumulate: always 16 loads in flight, masked adds
__device__ __forceinline__ void gather16(float4& acc, const unsigned short* __restrict__ zz,
                                         const int* __restrict__ csr,
                                         int e0, int e1, size_t c4) {
    for (int e = e0; e < e1; e += 16) {
        int idx[16];
        #pragma unroll
        for (int k = 0; k < 16; k++) {
            int ee = e + k;
            idx[k] = csr[ee < e1 ? ee : e1 - 1];
        }
        ushort4 vv[16];
        #pragma unroll
        for (int k = 0; k < 16; k++)
            vv[k] = *(const ushort4*)(zz + (size_t)idx[k] * D + c4);
        #pragma unroll
        for (int k = 0; k < 16; k++) {
            if (e + k < e1) acc4(acc, vv[k]);
        }
    }
}

// ---------------- conv1 fused: agg(z)+b1a+relu, @w1b+b1b relu, @w2a -> u (bf16) ----------------
__global__ __launch_bounds__(256, 6) void k_conv1(const unsigned short* __restrict__ z,
                                                  const int* __restrict__ offs,
                                                  const int* __restrict__ csr,
                                                  const float* __restrict__ b1a,
                                                  const float* __restrict__ w1b,
                                                  const float* __restrict__ b1b,
                                                  const float* __restrict__ w2a,
                                                  unsigned short* __restrict__ u) {
    __shared__ unsigned short w1s[D][D];   // 8 KB bf16
    __shared__ unsigned short w2s[D][D];   // 8 KB bf16
    __shared__ float h1s[16][D + 1];
    __shared__ float h2s[16][D + 1];
    int t = threadIdx.x;
    int r = t >> 4, c = t & 15;
    {
        for (int i = t; i < (D * D) / 4; i += 256) {
            float4 a = ((const float4*)w1b)[i];
            ushort4 p; p.x = f2bf(a.x); p.y = f2bf(a.y); p.z = f2bf(a.z); p.w = f2bf(a.w);
            *(ushort4*)&(&w1s[0][0])[i * 4] = p;
            float4 b = ((const float4*)w2a)[i];
            ushort4 q; q.x = f2bf(b.x); q.y = f2bf(b.y); q.z = f2bf(b.z); q.w = f2bf(b.w);
            *(ushort4*)&(&w2s[0][0])[i * 4] = q;
        }
    }
    float4 vb1a = ((const float4*)b1a)[c];
    float4 vb1b = ((const float4*)b1b)[c];
    __syncthreads();

    const size_t c4 = (size_t)(c * 4);
    for (int base = blockIdx.x * 16; base < N_NODES; base += gridDim.x * 16) {
        int node = base + r;   // N_NODES % 16 == 0
        float4 acc = {vb1a.x, vb1a.y, vb1a.z, vb1a.w};
        acc4(acc, *(const ushort4*)(z + (size_t)node * D + c4));
        int e0 = offs[node], e1 = offs[node + 1];
        gather16(acc, z, csr, e0, e1, c4);
        h1s[r][c * 4 + 0] = fmaxf(acc.x, 0.f);
        h1s[r][c * 4 + 1] = fmaxf(acc.y, 0.f);
        h1s[r][c * 4 + 2] = fmaxf(acc.z, 0.f);
        h1s[r][c * 4 + 3] = fmaxf(acc.w, 0.f);
        __syncthreads();
        // --- h2 = relu(h1 @ w1b + b1b) ---
        float4 a2 = vb1b;
        for (int k = 0; k < D; k++) {
            float hv = h1s[r][k];
            ushort4 wv = *(const ushort4*)&w1s[k][c * 4];
            a2.x += hv * bf2f(wv.x); a2.y += hv * bf2f(wv.y);
            a2.z += hv * bf2f(wv.z); a2.w += hv * bf2f(wv.w);
        }
        h2s[r][c * 4 + 0] = fmaxf(a2.x, 0.f);
        h2s[r][c * 4 + 1] = fmaxf(a2.y, 0.f);
        h2s[r][c * 4 + 2] = fmaxf(a2.z, 0.f);
        h2s[r][c * 4 + 3] = fmaxf(a2.w, 0.f);
        __syncthreads();
        // --- u = h2 @ w2a  (bias b2a applied in conv2 agg), u stored bf16 ---
        float4 a3 = {0.f, 0.f, 0.f, 0.f};
        for (int k = 0; k < D; k++) {
            float hv = h2s[r][k];
            ushort4 wv = *(const ushort4*)&w2s[k][c * 4];
            a3.x += hv * bf2f(wv.x); a3.y += hv * bf2f(wv.y);
            a3.z += hv * bf2f(wv.z); a3.w += hv * bf2f(wv.w);
        }
        ushort4 p;
        p.x = f2bf(a3.x); p.y = f2bf(a3.y); p.z = f2bf(a3.z); p.w = f2bf(a3.w);
        *(ushort4*)(u + (size_t)node * D + c4) = p;
        __syncthreads();
    }
}

// ---------------- conv2 fused: agg(u) + b2a + relu -> column sum ----------------
__global__ __launch_bounds__(256) void k_conv2(const unsigned short* __restrict__ u,
                                               const int* __restrict__ offs,
                                               const int* __restrict__ csr,
                                               const float* __restrict__ b2a,
                                               float* __restrict__ colsum) {
    __shared__ float red[16][D + 1];
    int t = threadIdx.x;
    int r = t >> 4, c = t & 15;
    float4 vb = ((const float4*)b2a)[c];
    float4 cs = {0.f, 0.f, 0.f, 0.f};
    const size_t c4 = (size_t)(c * 4);
    for (int base = blockIdx.x * 16; base < N_NODES; base += gridDim.x * 16) {
        int node = base + r;
        float4 acc = {vb.x, vb.y, vb.z, vb.w};
        acc4(acc, *(const ushort4*)(u + (size_t)node * D + c4));
        int e0 = offs[node], e1 = offs[node + 1];
        gather16(acc, u, csr, e0, e1, c4);
        cs.x += fmaxf(acc.x, 0.f); cs.y += fmaxf(acc.y, 0.f);
        cs.z += fmaxf(acc.z, 0.f); cs.w += fmaxf(acc.w, 0.f);
    }
    red[r][c * 4 + 0] = cs.x; red[r][c * 4 + 1] = cs.y;
    red[r][c * 4 + 2] = cs.z; red[r][c * 4 + 3] = cs.w;
    __syncthreads();
    if (r == 0) {
        float4 tot = {0.f, 0.f, 0.f, 0.f};
        for (int rr = 0; rr < 16; rr++) {
            tot.x += red[rr][c * 4 + 0]; tot.y += red[rr][c * 4 + 1];
            tot.z += red[rr][c * 4 + 2]; tot.w += red[rr][c * 4 + 3];
        }
        atomicAdd(&colsum[c * 4 + 0], tot.x);
        atomicAdd(&colsum[c * 4 + 1], tot.y);
        atomicAdd(&colsum[c * 4 + 2], tot.z);
        atomicAdd(&colsum[c * 4 + 3], tot.w);
    }
}

// ---------------- out = colsum @ w2b + N * b2b ----------------
__global__ void k_final(const float* __restrict__ colsum, const float* __restrict__ w2b,
                        const float* __restrict__ b2b, float* __restrict__ out) {
    int j = threadIdx.x;
    float acc = (float)N_NODES * b2b[j];
    for (int k = 0; k < D; k++) acc += colsum[k] * w2b[k * D + j];
    out[j] = acc;
}

// ---------------- launch ----------------

extern "C" void kernel_launch(void* const* d_in, const int* in_sizes, int n_in,
                              void* d_out, int out_size, void* d_ws, size_t ws_size,
                              hipStream_t stream) {
    const float* x   = (const float*)d_in[0];
    const int*   ei  = (const int*)d_in[1];
    const float* w1a = (const float*)d_in[2];
    const float* b1a = (const float*)d_in[3];
    const float* w1b = (const float*)d_in[4];
    const float* b1b = (const float*)d_in[5];
    const float* w2a = (const float*)d_in[6];
    const float* b2a = (const float*)d_in[7];
    const float* w2b = (const float*)d_in[8];
    const float* b2b = (const float*)d_in[9];
    float* out = (float*)d_out;

    const int* srcp = ei;
    const int* dstp = ei + N_EDGES;

    char* ws = (char*)d_ws;
    unsigned short* z = (unsigned short*)(ws + 0);        // 12,800,000 B
    unsigned short* u = (unsigned short*)(ws + 12800000); // 12,800,000 B
    uint2* tmp    = (uint2*)(ws + 25600000);              // 12,800,000 B
    int*   csr    = (int*)(ws + 38400000);                // 6,400,000 B
    int*   bh     = (int*)(ws + 44800000);                // 1,564,000 B
    int*   offs   = (int*)(ws + 46364000);                // 400,004 B
    float* colsum = (float*)(ws + 46764032);              // 256 B
    int*   part   = (int*)(ws + 46764288);                // 1,528 B

    hipMemsetAsync(colsum, 0, D * sizeof(float), stream);

    k_hist1   <<<NBLK, 256, 0, stream>>>(dstp, bh);
    k_scanA   <<<SC_NB, 256, 0, stream>>>(bh, part);
    k_scanB   <<<1, 512, 0, stream>>>(part);
    k_scanC   <<<SC_NB, 256, 0, stream>>>(bh, part);
    k_scatter1<<<NBLK, 256, 0, stream>>>(srcp, dstp, bh, tmp);
    k_build   <<<NB2, 256, 0, stream>>>(tmp, bh, offs, csr);

    k_gemm1<<<2048, 256, 0, stream>>>(x, w1a, z);
    k_conv1<<<2048, 256, 0, stream>>>(z, offs, csr, b1a, w1b, b1b, w2a, u);
    k_conv2<<<2048, 256, 0, stream>>>(u, offs, csr, b2a, colsum);
    k_final<<<1, 64, 0, stream>>>(colsum, w2b, b2b, out);
}

// Round 7
// 485.339 us; speedup vs baseline: 2.3399x; 1.0156x over previous
//
#include <hip/hip_runtime.h>

#define N_NODES 100000
#define N_EDGES 1600000
#define D_IN 128
#define D 64

#define NBLK 1000          // scatter blocks
#define EPB  1600          // edges per scatter block (NBLK*EPB == N_EDGES)
#define NB2  391           // coarse buckets: dst>>8, max 99999>>8 = 390
#define SC_M  (NB2 * NBLK)                  // 391,000 scan elements
#define SC_CH 1024                          // elements per scan chunk
#define SC_NB ((SC_M + SC_CH - 1) / SC_CH)  // 382 chunks

__device__ __forceinline__ float bf2f(unsigned short u) {
    union { unsigned int i; float f; } q; q.i = ((unsigned int)u) << 16; return q.f;
}
__device__ __forceinline__ unsigned short f2bf(float f) {
    unsigned int u = __float_as_uint(f);
    unsigned int r = (u + 0x7FFFu + ((u >> 16) & 1u)) >> 16;   // RNE
    return (unsigned short)r;
}
__device__ __forceinline__ void acc4(float4& a, ushort4 v) {
    a.x += bf2f(v.x); a.y += bf2f(v.y); a.z += bf2f(v.z); a.w += bf2f(v.w);
}

// ============ CSR build: two-level counting sort, LDS atomics only ============

// A1: per-block histogram over coarse buckets
__global__ __launch_bounds__(256) void k_hist1(const int* __restrict__ dst,
                                               int* __restrict__ bh) {
    __shared__ int h[NB2];
    int t = threadIdx.x;
    for (int i = t; i < NB2; i += 256) h[i] = 0;
    __syncthreads();
    int base = blockIdx.x * EPB;
    for (int i = t; i < EPB; i += 256) atomicAdd(&h[dst[base + i] >> 8], 1);
    __syncthreads();
    for (int i = t; i < NB2; i += 256) bh[i * NBLK + blockIdx.x] = h[i];
}

// A2a: per-chunk sums (1024 elements / block of 256, int4 loads)
__global__ __launch_bounds__(256) void k_scanA(const int* __restrict__ bh,
                                               int* __restrict__ part) {
    __shared__ int s[256];
    int t = threadIdx.x;
    int base = blockIdx.x * SC_CH + t * 4;
    int sum = 0;
    if (base + 3 < SC_M) {
        int4 v = *(const int4*)(bh + base);
        sum = (v.x + v.y) + (v.z + v.w);
    } else {
        for (int k = 0; k < 4; k++) if (base + k < SC_M) sum += bh[base + k];
    }
    s[t] = sum;
    __syncthreads();
    for (int o = 128; o > 0; o >>= 1) {
        if (t < o) s[t] += s[t + o];
        __syncthreads();
    }
    if (t == 0) part[blockIdx.x] = s[0];
}

// A2b: exclusive scan of the 382 chunk sums (1 block)
__global__ __launch_bounds__(512) void k_scanB(int* __restrict__ part) {
    __shared__ int s[512];
    int t = threadIdx.x;
    int v = (t < SC_NB) ? part[t] : 0;
    s[t] = v;
    __syncthreads();
    for (int o = 1; o < 512; o <<= 1) {
        int x = (t >= o) ? s[t - o] : 0;
        __syncthreads();
        s[t] += x;
        __syncthreads();
    }
    if (t < SC_NB) part[t] = s[t] - v;   // exclusive
}

// A2c: local exclusive scan + chunk base, write back in place
__global__ __launch_bounds__(256) void k_scanC(int* __restrict__ bh,
                                               const int* __restrict__ part) {
    __shared__ int s[256];
    int t = threadIdx.x;
    int base = blockIdx.x * SC_CH + t * 4;
    int4 v = {0, 0, 0, 0};
    if (base + 3 < SC_M) v = *(const int4*)(bh + base);
    else { for (int k = 0; k < 4; k++) if (base + k < SC_M) (&v.x)[k] = bh[base + k]; }
    int sum = (v.x + v.y) + (v.z + v.w);
    s[t] = sum;
    __syncthreads();
    for (int o = 1; o < 256; o <<= 1) {
        int x = (t >= o) ? s[t - o] : 0;
        __syncthreads();
        s[t] += x;
        __syncthreads();
    }
    int run = part[blockIdx.x] + s[t] - sum;   // exclusive base for this thread
    int4 w;
    w.x = run; run += v.x;
    w.y = run; run += v.y;
    w.z = run; run += v.z;
    w.w = run;
    if (base + 3 < SC_M) *(int4*)(bh + base) = w;
    else { for (int k = 0; k < 4; k++) if (base + k < SC_M) bh[base + k] = (&w.x)[k]; }
}

// A3: scatter (dst,src) pairs into bucket-sorted tmp
__global__ __launch_bounds__(256) void k_scatter1(const int* __restrict__ src,
                                                  const int* __restrict__ dst,
                                                  const int* __restrict__ bh,
                                                  uint2* __restrict__ tmp) {
    __shared__ int cur[NB2];
    int t = threadIdx.x;
    for (int i = t; i < NB2; i += 256) cur[i] = bh[i * NBLK + blockIdx.x];
    __syncthreads();
    int base = blockIdx.x * EPB;
    for (int i = t; i < EPB; i += 256) {
        int d = dst[base + i];
        int sv = src[base + i];
        int p = atomicAdd(&cur[d >> 8], 1);
        tmp[p] = make_uint2((unsigned)d, (unsigned)sv);
    }
}

// B1: per-bucket node degrees + padded bucket sums
__global__ __launch_bounds__(256) void k_padsum(const uint2* __restrict__ tmp,
                                                const int* __restrict__ bh,
                                                int* __restrict__ degarr,
                                                int* __restrict__ pb) {
    __shared__ int deg[256];
    __shared__ int s[256];
    int b = blockIdx.x, t = threadIdx.x;
    int e0 = bh[b * NBLK];
    int e1 = (b == NB2 - 1) ? N_EDGES : bh[(b + 1) * NBLK];
    deg[t] = 0;
    __syncthreads();
    for (int i = e0 + t; i < e1; i += 256) atomicAdd(&deg[tmp[i].x & 255u], 1);
    __syncthreads();
    int node = b * 256 + t;
    int d = (node < N_NODES) ? deg[t] : 0;
    if (node < N_NODES) degarr[node] = d;
    int dp = (d + 15) & ~15;
    s[t] = dp;
    __syncthreads();
    for (int o = 128; o > 0; o >>= 1) {
        if (t < o) s[t] += s[t + o];
        __syncthreads();
    }
    if (t == 0) pb[b] = s[0];
}

// B2: exclusive scan of 391 padded bucket sums
__global__ __launch_bounds__(512) void k_scanP(int* __restrict__ pb) {
    __shared__ int s[512];
    int t = threadIdx.x;
    int v = (t < NB2) ? pb[t] : 0;
    s[t] = v;
    __syncthreads();
    for (int o = 1; o < 512; o <<= 1) {
        int x = (t >= o) ? s[t - o] : 0;
        __syncthreads();
        s[t] += x;
        __syncthreads();
    }
    if (t < NB2) pb[t] = s[t] - v;   // exclusive
}

// B3: padded CSR build (pad slots -> N_NODES = zero row)
__global__ __launch_bounds__(256) void k_build2(const uint2* __restrict__ tmp,
                                                const int* __restrict__ bh,
                                                const int* __restrict__ degarr,
                                                const int* __restrict__ pb,
                                                int* __restrict__ offs,
                                                int* __restrict__ csr) {
    __shared__ int s[256];
    __shared__ int startp[256];
    __shared__ int cur[256];
    int b = blockIdx.x, t = threadIdx.x;
    int e0 = bh[b * NBLK];
    int e1 = (b == NB2 - 1) ? N_EDGES : bh[(b + 1) * NBLK];
    int node = b * 256 + t;
    int d = (node < N_NODES) ? degarr[node] : 0;
    int dp = (d + 15) & ~15;
    s[t] = dp;
    __syncthreads();
    for (int o = 1; o < 256; o <<= 1) {
        int x = (t >= o) ? s[t - o] : 0;
        __syncthreads();
        s[t] += x;
        __syncthreads();
    }
    int st = pb[b] + s[t] - dp;    // padded exclusive start
    startp[t] = st;
    cur[t] = st;
    if (node < N_NODES) {
        offs[node] = st;
        if (node == N_NODES - 1) offs[N_NODES] = st + dp;
    }
    __syncthreads();
    for (int i = e0 + t; i < e1; i += 256) {
        uint2 p = tmp[i];
        int pos = atomicAdd(&cur[p.x & 255u], 1);
        csr[pos] = (int)p.y;
    }
    __syncthreads();
    int end = startp[t] + dp;
    for (int p = cur[t]; p < end; p++) csr[p] = N_NODES;   // zero-row index
}

// ---------------- z = x @ w1a  (128 -> 64, no bias), z stored bf16 ----------------
__global__ __launch_bounds__(256) void k_gemm1(const float* __restrict__ x,
                                               const float* __restrict__ w,
                                               unsigned short* __restrict__ z) {
    __shared__ float ws[D_IN][D];        // 32 KB
    __shared__ float xs[16][D_IN + 1];
    int t = threadIdx.x;
    {
        const float4* w4 = (const float4*)w;
        float4* s4 = (float4*)&ws[0][0];
        for (int i = t; i < (D_IN * D) / 4; i += 256) s4[i] = w4[i];
    }
    int r = t >> 4, c = t & 15;
    __syncthreads();
    for (int base = blockIdx.x * 16; base < N_NODES; base += gridDim.x * 16) {
        for (int i = t; i < 16 * (D_IN / 4); i += 256) {
            int row = i >> 5, k4 = i & 31;
            float4 v = ((const float4*)(x + (size_t)(base + row) * D_IN))[k4];
            xs[row][k4 * 4 + 0] = v.x; xs[row][k4 * 4 + 1] = v.y;
            xs[row][k4 * 4 + 2] = v.z; xs[row][k4 * 4 + 3] = v.w;
        }
        __syncthreads();
        float4 acc = {0.f, 0.f, 0.f, 0.f};
        for (int k = 0; k < D_IN; k++) {
            float xv = xs[r][k];
            float4 wv = *(const float4*)&ws[k][c * 4];
            acc.x += xv * wv.x; acc.y += xv * wv.y;
            acc.z += xv * wv.z; acc.w += xv * wv.w;
        }
        ushort4 p;
        p.x = f2bf(acc.x); p.y = f2bf(acc.y); p.z = f2bf(acc.z); p.w = f2bf(acc.w);
        *(ushort4*)(z + (size_t)(base + r) * D + c * 4) = p;
        __syncthreads();
    }
}

// unconditional padded depth-16 gather: e1-e0 is a multiple of 16; pad rows are zeros
__device__ __forceinline__ void gather16p(float4& acc, const unsigned short* __restrict__ zz,
                                          const int* __restrict__ csr,
                                          int e0, int e1, size_t c4) {
    for (int e = e0; e < e1; e += 16) {
        int idx[16];
        *(int4*)(&idx[0])  = *(const int4*)(csr + e);
        *(int4*)(&idx[4])  = *(const int4*)(csr + e + 4);
        *(int4*)(&idx[8])  = *(const int4*)(csr + e + 8);
        *(int4*)(&idx[12]) = *(const int4*)(csr + e + 12);
        ushort4 vv[16];
        #pragma unroll
        for (int k = 0; k < 16; k++)
            vv[k] = *(const ushort4*)(zz + (size_t)idx[k] * D + c4);
        #pragma unroll
        for (int k = 0; k < 16; k++) acc4(acc, vv[k]);
    }
}

// ---------------- conv1 fused: agg(z)+b1a+relu, @w1b+b1b relu, @w2a -> u (bf16) ----------------
__global__ __launch_bounds__(256, 6) void k_conv1(const unsigned short* __restrict__ z,
                                                  const int* __restrict__ offs,
                                                  const int* __restrict__ csr,
                                                  const float* __restrict__ b1a,
                                                  const float* __restrict__ w1b,
                                                  const float* __restrict__ b1b,
                                                  const float* __restrict__ w2a,
                                                  unsigned short* __restrict__ u) {
    __shared__ unsigned short w1s[D][D];   // 8 KB bf16
    __shared__ unsigned short w2s[D][D];   // 8 KB bf16
    __shared__ float h1s[16][D + 1];
    __shared__ float h2s[16][D + 1];
    int t = threadIdx.x;
    int r = t >> 4, c = t & 15;
    {
        for (int i = t; i < (D * D) / 4; i += 256) {
            float4 a = ((const float4*)w1b)[i];
            ushort4 p; p.x = f2bf(a.x); p.y = f2bf(a.y); p.z = f2bf(a.z); p.w = f2bf(a.w);
            *(ushort4*)&(&w1s[0][0])[i * 4] = p;
            float4 b = ((const float4*)w2a)[i];
            ushort4 q; q.x = f2bf(b.x); q.y = f2bf(b.y); q.z = f2bf(b.z); q.w = f2bf(b.w);
            *(ushort4*)&(&w2s[0][0])[i * 4] = q;
        }
    }
    float4 vb1a = ((const float4*)b1a)[c];
    float4 vb1b = ((const float4*)b1b)[c];
    __syncthreads();

    const size_t c4 = (size_t)(c * 4);
    for (int base = blockIdx.x * 16; base < N_NODES; base += gridDim.x * 16) {
        int node = base + r;   // N_NODES % 16 == 0
        float4 acc = {vb1a.x, vb1a.y, vb1a.z, vb1a.w};
        acc4(acc, *(const ushort4*)(z + (size_t)node * D + c4));
        int e0 = offs[node], e1 = offs[node + 1];
        gather16p(acc, z, csr, e0, e1, c4);
        h1s[r][c * 4 + 0] = fmaxf(acc.x, 0.f);
        h1s[r][c * 4 + 1] = fmaxf(acc.y, 0.f);
        h1s[r][c * 4 + 2] = fmaxf(acc.z, 0.f);
        h1s[r][c * 4 + 3] = fmaxf(acc.w, 0.f);
        __syncthreads();
        // --- h2 = relu(h1 @ w1b + b1b) ---
        float4 a2 = vb1b;
        for (int k = 0; k < D; k++) {
            float hv = h1s[r][k];
            ushort4 wv = *(const ushort4*)&w1s[k][c * 4];
            a2.x += hv * bf2f(wv.x); a2.y += hv * bf2f(wv.y);
            a2.z += hv * bf2f(wv.z); a2.w += hv * bf2f(wv.w);
        }
        h2s[r][c * 4 + 0] = fmaxf(a2.x, 0.f);
        h2s[r][c * 4 + 1] = fmaxf(a2.y, 0.f);
        h2s[r][c * 4 + 2] = fmaxf(a2.z, 0.f);
        h2s[r][c * 4 + 3] = fmaxf(a2.w, 0.f);
        __syncthreads();
        // --- u = h2 @ w2a  (bias b2a applied in conv2 agg), u stored bf16 ---
        float4 a3 = {0.f, 0.f, 0.f, 0.f};
        for (int k = 0; k < D; k++) {
            float hv = h2s[r][k];
            ushort4 wv = *(const ushort4*)&w2s[k][c * 4];
            a3.x += hv * bf2f(wv.x); a3.y += hv * bf2f(wv.y);
            a3.z += hv * bf2f(wv.z); a3.w += hv * bf2f(wv.w);
        }
        ushort4 p;
        p.x = f2bf(a3.x); p.y = f2bf(a3.y); p.z = f2bf(a3.z); p.w = f2bf(a3.w);
        *(ushort4*)(u + (size_t)node * D + c4) = p;
        __syncthreads();
    }
}

// ---------------- conv2 fused: agg(u) + b2a + relu -> column sum ----------------
__global__ __launch_bounds__(256) void k_conv2(const unsigned short* __restrict__ u,
                                               const int* __restrict__ offs,
                                               const int* __restrict__ csr,
                                               const float* __restrict__ b2a,
                                               float* __restrict__ colsum) {
    __shared__ float red[16][D + 1];
    int t = threadIdx.x;
    int r = t >> 4, c = t & 15;
    float4 vb = ((const float4*)b2a)[c];
    float4 cs = {0.f, 0.f, 0.f, 0.f};
    const size_t c4 = (size_t)(c * 4);
    for (int base = blockIdx.x * 16; base < N_NODES; base += gridDim.x * 16) {
        int node = base + r;
        float4 acc = {vb.x, vb.y, vb.z, vb.w};
        acc4(acc, *(const ushort4*)(u + (size_t)node * D + c4));
        int e0 = offs[node], e1 = offs[node + 1];
        gather16p(acc, u, csr, e0, e1, c4);
        cs.x += fmaxf(acc.x, 0.f); cs.y += fmaxf(acc.y, 0.f);
        cs.z += fmaxf(acc.z, 0.f); cs.w += fmaxf(acc.w, 0.f);
    }
    red[r][c * 4 + 0] = cs.x; red[r][c * 4 + 1] = cs.y;
    red[r][c * 4 + 2] = cs.z; red[r][c * 4 + 3] = cs.w;
    __syncthreads();
    if (r == 0) {
        float4 tot = {0.f, 0.f, 0.f, 0.f};
        for (int rr = 0; rr < 16; rr++) {
            tot.x += red[rr][c * 4 + 0]; tot.y += red[rr][c * 4 + 1];
            tot.z += red[rr][c * 4 + 2]; tot.w += red[rr][c * 4 + 3];
        }
        atomicAdd(&colsum[c * 4 + 0], tot.x);
        atomicAdd(&colsum[c * 4 + 1], tot.y);
        atomicAdd(&colsum[c * 4 + 2], tot.z);
        atomicAdd(&colsum[c * 4 + 3], tot.w);
    }
}

// ---------------- out = colsum @ w2b + N * b2b ----------------
__global__ void k_final(const float* __restrict__ colsum, const float* __restrict__ w2b,
                        const float* __restrict__ b2b, float* __restrict__ out) {
    int j = threadIdx.x;
    float acc = (float)N_NODES * b2b[j];
    for (int k = 0; k < D; k++) acc += colsum[k] * w2b[k * D + j];
    out[j] = acc;
}

// ---------------- launch ----------------

extern "C" void kernel_launch(void* const* d_in, const int* in_sizes, int n_in,
                              void* d_out, int out_size, void* d_ws, size_t ws_size,
                              hipStream_t stream) {
    const float* x   = (const float*)d_in[0];
    const int*   ei  = (const int*)d_in[1];
    const float* w1a = (const float*)d_in[2];
    const float* b1a = (const float*)d_in[3];
    const float* w1b = (const float*)d_in[4];
    const float* b1b = (const float*)d_in[5];
    const float* w2a = (const float*)d_in[6];
    const float* b2a = (const float*)d_in[7];
    const float* w2b = (const float*)d_in[8];
    const float* b2b = (const float*)d_in[9];
    float* out = (float*)d_out;

    const int* srcp = ei;
    const int* dstp = ei + N_EDGES;

    char* ws = (char*)d_ws;
    unsigned short* z = (unsigned short*)(ws + 0);        // (N+1) rows: 12,800,256 B
    unsigned short* u = (unsigned short*)(ws + 12800256); // 12,800,256 B
    uint2* tmp    = (uint2*)(ws + 25600512);              // 12,800,000 B
    int*   csr    = (int*)(ws + 38400512);                // padded, <= 12,400,000 B
    int*   bh     = (int*)(ws + 51200512);                // 1,564,000 B
    int*   degarr = (int*)(ws + 52764512);                // 400,000 B
    int*   offs   = (int*)(ws + 53164896);                // 400,064 B
    int*   pb     = (int*)(ws + 53564960);                // 2,048 B
    int*   part   = (int*)(ws + 53567008);                // 2,048 B
    float* colsum = (float*)(ws + 53569056);              // 256 B

    hipMemsetAsync(colsum, 0, D * sizeof(float), stream);
    hipMemsetAsync(z + (size_t)N_NODES * D, 0, D * sizeof(unsigned short), stream);
    hipMemsetAsync(u + (size_t)N_NODES * D, 0, D * sizeof(unsigned short), stream);

    k_hist1   <<<NBLK, 256, 0, stream>>>(dstp, bh);
    k_scanA   <<<SC_NB, 256, 0, stream>>>(bh, part);
    k_scanB   <<<1, 512, 0, stream>>>(part);
    k_scanC   <<<SC_NB, 256, 0, stream>>>(bh, part);
    k_scatter1<<<NBLK, 256, 0, stream>>>(srcp, dstp, bh, tmp);
    k_padsum  <<<NB2, 256, 0, stream>>>(tmp, bh, degarr, pb);
    k_scanP   <<<1, 512, 0, stream>>>(pb);
    k_build2  <<<NB2, 256, 0, stream>>>(tmp, bh, degarr, pb, offs, csr);

    k_gemm1<<<2048, 256, 0, stream>>>(x, w1a, z);
    k_conv1<<<2048, 256, 0, stream>>>(z, offs, csr, b1a, w1b, b1b, w2a, u);
    k_conv2<<<2048, 256, 0, stream>>>(u, offs, csr, b2a, colsum);
    k_final<<<1, 64, 0, stream>>>(colsum, w2b, b2b, out);
}